// Round 8
// baseline (163.349 us; speedup 1.0000x reference)
//
#include <hip/hip_runtime.h>
#include <hip/hip_bf16.h>
#include <stdint.h>
#include <stddef.h>

typedef unsigned short u16;
typedef unsigned int   u32;
typedef __attribute__((ext_vector_type(8))) short bf16x8;  // 8 bf16 = 4 VGPRs
typedef __attribute__((ext_vector_type(4))) float f32x4;   // MFMA C/D

#define LOG2E   1.44269504f
#define EXP_OFF 23.0831206f   // 16 * log2(e)

static __device__ __forceinline__ float bf2f(u16 v) {
    u32 u = ((u32)v) << 16; float f; __builtin_memcpy(&f, &u, 4); return f;
}
static __device__ __forceinline__ u16 f2bf(float f) {
    u32 u; __builtin_memcpy(&u, &f, 4);
    u32 r = (u + 0x7fffu + ((u >> 16) & 1u)) >> 16; return (u16)r;
}
static __device__ __forceinline__ float as_f(u32 u) { float f; __builtin_memcpy(&f, &u, 4); return f; }
static __device__ __forceinline__ u32   as_u(float f) { u32 u; __builtin_memcpy(&u, &f, 4); return u; }

// async global->LDS, 16B per lane (dest = wave-uniform base + lane*16)
static __device__ __forceinline__ void gload_lds16(const u16* g, u16* l) {
    __builtin_amdgcn_global_load_lds(
        (const __attribute__((address_space(1))) void*)g,
        (__attribute__((address_space(3))) void*)l, 16, 0, 0);
}

// fp32-vs-bf16 input detection (wave 0)
static __device__ __forceinline__ int detect_f32_wave0(const void* x, int t) {
    const u32* xw = (const u32*)x;
    int bad = 0;
    #pragma unroll
    for (int k = 0; k < 4; ++k) {
        u32 wv = xw[(t << 2) + k];
        int e = (wv >> 7) & 0xff;
        bad += (e >= 160);
    }
    unsigned long long m = __ballot(bad > 0);
    return (__popcll(m) >= 8) ? 1 : 0;
}

// V workspace layout (pre-fragmented for MFMA B-operand, per batch):
//   elem_addr = cblk*65536 + jblk*512 + (quad4*16 + clo)*8 + jlo
//   where c = cblk*16 + clo, j = jblk*32 + quad4*8 + jlo.
// A wave B-frag load (lane = quad*16+n16 reads 16B) is 1KB fully contiguous.

// ---------------------------------------------------------------------------
// Kernel 1 (MFMA proj, unchanged — verified at R1):
// ---------------------------------------------------------------------------
__global__ __launch_bounds__(256) void qkv_proj_mfma(
    const void* __restrict__ x,
    const void* __restrict__ Wq, const void* __restrict__ bq,
    const void* __restrict__ Wk, const void* __restrict__ bk,
    const void* __restrict__ Wv, const void* __restrict__ bv,
    u16* __restrict__ qws, u16* __restrict__ kws, u16* __restrict__ vws,
    int n_off, int nshiftp)
{
    __shared__ u16 Wl[64 * 256];   // 32 KB, swizzled bf16 W-slice
    __shared__ int dtf;

    const int t    = threadIdx.x;
    const int bid  = blockIdx.x;
    const int n_w  = bid & ((1 << nshiftp) - 1);
    const int rest = bid >> nshiftp;
    const int g    = rest % 5;        // 0 = q+k, 1..4 = v quarters
    const int it   = rest / 5;        // i-tile (64 i)
    const int n_g  = n_off + n_w;
    const int i0   = it << 6;

    if (t < 64) { int f = detect_f32_wave0(x, t); if (t == 0) dtf = f; }
    __syncthreads();
    const bool isf32 = (dtf != 0);

    // ---- stage W slice (64 rows x 256 cols) into LDS, swizzled bf16 ----
    #pragma unroll
    for (int k = 0; k < 16; ++k) {
        int idx  = t + (k << 8);
        int row  = idx >> 6;            // 0..63 (wave-uniform per k)
        int col4 = (idx & 63) << 2;     // 0..252 step 4
        const void* src; int srow;
        if (g == 0) {
            if (row < 32) { src = Wq; srow = row; }
            else          { src = Wk; srow = row - 32; }
        } else { src = Wv; srow = ((g - 1) << 6) + row; }
        ushort4 h;
        if (isf32) {
            float4 wv = *((const float4*)((const float*)src + srow * 256 + col4));
            h.x = f2bf(wv.x); h.y = f2bf(wv.y); h.z = f2bf(wv.z); h.w = f2bf(wv.w);
        } else {
            h = *((const ushort4*)((const u16*)src + srow * 256 + col4));
        }
        *(ushort4*)&Wl[(row << 8) + (col4 ^ ((row & 7) << 3))] = h;
    }
    __syncthreads();

    const int lane = t & 63;
    const int w    = t >> 6;          // wave -> i-frag
    const int n16  = lane & 15;
    const int quad = lane >> 4;
    const int i_b  = i0 + (w << 4);
    const int i    = i_b + n16;
    const int swz  = (n16 & 7) << 3;

    f32x4 acc[4];
    #pragma unroll
    for (int f = 0; f < 4; ++f) acc[f] = (f32x4){0.f, 0.f, 0.f, 0.f};

    // ---- k-loop: 8 chunks of 32 c; A direct-global, B from LDS ----
    if (isf32) {
        const float* xp = (const float*)x
            + (((size_t)(n_g * 256 + (quad << 3))) << 12) + i;
        float af[8];
        #pragma unroll
        for (int e = 0; e < 8; ++e) af[e] = xp[(size_t)e << 12];
        #pragma unroll
        for (int c8 = 0; c8 < 8; ++c8) {
            bf16x8 a;
            #pragma unroll
            for (int e = 0; e < 8; ++e) a[e] = (short)f2bf(af[e]);
            if (c8 < 7) {
                const float* xn = xp + (((size_t)(c8 + 1) << 5) << 12);
                #pragma unroll
                for (int e = 0; e < 8; ++e) af[e] = xn[(size_t)e << 12];
            }
            const int c0 = c8 << 5;
            #pragma unroll
            for (int f = 0; f < 4; ++f) {
                const int brow = (f << 4) + n16;
                bf16x8 b = *(const bf16x8*)
                    &Wl[(brow << 8) + ((c0 + (quad << 3)) ^ swz)];
                acc[f] = __builtin_amdgcn_mfma_f32_16x16x32_bf16(a, b, acc[f], 0, 0, 0);
            }
        }
    } else {
        const u16* xp = (const u16*)x
            + (((size_t)(n_g * 256 + (quad << 3))) << 12) + i;
        u16 af[8];
        #pragma unroll
        for (int e = 0; e < 8; ++e) af[e] = xp[(size_t)e << 12];
        #pragma unroll
        for (int c8 = 0; c8 < 8; ++c8) {
            bf16x8 a;
            #pragma unroll
            for (int e = 0; e < 8; ++e) a[e] = (short)af[e];
            if (c8 < 7) {
                const u16* xn = xp + (((size_t)(c8 + 1) << 5) << 12);
                #pragma unroll
                for (int e = 0; e < 8; ++e) af[e] = xn[(size_t)e << 12];
            }
            const int c0 = c8 << 5;
            #pragma unroll
            for (int f = 0; f < 4; ++f) {
                const int brow = (f << 4) + n16;
                bf16x8 b = *(const bf16x8*)
                    &Wl[(brow << 8) + ((c0 + (quad << 3)) ^ swz)];
                acc[f] = __builtin_amdgcn_mfma_f32_16x16x32_bf16(a, b, acc[f], 0, 0, 0);
            }
        }
    }

    // ---- epilogue: D frag is (col = n16 = och-local, row = quad*4+r = i) ----
    if (g == 0) {
        #pragma unroll
        for (int f = 0; f < 4; ++f) {
            const int ol   = (f << 4) + n16;     // 0..63
            const bool isq = (ol < 32);
            const int och  = isq ? ol : (ol - 32);
            float bias;
            if (isf32) bias = ((const float*)(isq ? bq : bk))[och];
            else       bias = bf2f(((const u16*)(isq ? bq : bk))[och]);
            u16* dst = (isq ? qws : kws) + (((size_t)n_w) << 17) + och;
            const float scale = isq ? LOG2E : 1.0f;
            #pragma unroll
            for (int r = 0; r < 4; ++r) {
                const int ii = i_b + (quad << 2) + r;
                dst[(size_t)ii << 5] = f2bf((acc[f][r] + bias) * scale);
            }
        }
    } else {
        #pragma unroll
        for (int f = 0; f < 4; ++f) {
            const int c = ((g - 1) << 6) + (f << 4) + n16;   // c&15 == n16
            float bias = isf32 ? ((const float*)bv)[c]
                               : bf2f(((const u16*)bv)[c]);
            const int i4 = i_b + (quad << 2);
            ushort4 h;
            h.x = f2bf(acc[f][0] + bias);
            h.y = f2bf(acc[f][1] + bias);
            h.z = f2bf(acc[f][2] + bias);
            h.w = f2bf(acc[f][3] + bias);
            const size_t addr = ((size_t)n_w << 20)
                + ((size_t)(c >> 4) << 16)          // cblk*65536
                + ((size_t)(i4 >> 5) << 9)          // jblk*512
                + (size_t)((((((i4 & 31) >> 3) << 4) + (c & 15)) << 3) + (i4 & 7));
            *(ushort4*)(vws + addr) = h;
        }
    }
}

// ---------------------------------------------------------------------------
// Kernel 2 (v14): flash_mfma9 (52.4us) + K deduplication through LDS.
// v9 read K 4x redundantly (16 waves x 1KB, only 4KB distinct). Now waves
// 0-3 stage the 4KB K tile via global_load_lds (double-buffered, issued at
// phase start for tile+1, drained by the existing barrier); all 16 waves
// ds_read_b128 their frag. Per-CU L2 stream: 48KB -> 36KB per tile.
// Everything else identical to flash_mfma9 (PV map, softmax, epilogue).
// ---------------------------------------------------------------------------
__global__ __launch_bounds__(1024) void flash_mfma11(
    const u16* __restrict__ qws, const u16* __restrict__ kws,
    const u16* __restrict__ vws, void* __restrict__ out,
    const void* __restrict__ x, int n_off, int nshift)
{
    __shared__ __align__(16) char arena[17920];
    __shared__ __align__(16) u16 Klds[4096];   // 8 KB: 2 x 4KB K tiles
    __shared__ __align__(16) float lS[64];
    __shared__ int dtf;
    u16*   PsA  = (u16*)arena;                 // + par*4096 (elems)
    float* Dbuf = (float*)arena;               // epilogue alias

    const int t    = threadIdx.x;
    const int lane = t & 63;
    const int w    = t >> 6;          // 0..15
    const int n16  = lane & 15;
    const int quad = lane >> 4;
    const int bid  = blockIdx.x;
    const int n_w  = bid & ((1 << nshift) - 1);
    const int qt   = bid >> nshift;
    const int n_g  = n_off + n_w;
    const int i0   = qt << 6;

    if (t < 64) {
        int f = detect_f32_wave0(x, t);
        if (t == 0) dtf = f;
        lS[t] = 0.f;
    }

    const u16* qb = qws + (((size_t)n_w) << 17);
    const u16* kb = kws + (((size_t)n_w) << 17);
    const u16* vb = vws + (((size_t)n_w) << 20);

    // S decomposition
    const int qsub_s = w & 3;
    const int jsub   = w >> 2;
    // PV decomposition: 32 c x 32 j per wave
    const int cq = w & 7;
    const int jq = w >> 3;

    const bf16x8 qfrag =
        *(const bf16x8*)(qb + ((size_t)(i0 + (qsub_s << 4) + n16) << 5) + (quad << 3));

    f32x4 acc[4][2];
    #pragma unroll
    for (int a = 0; a < 4; ++a)
        #pragma unroll
        for (int b = 0; b < 2; ++b) acc[a][b] = (f32x4){0.f, 0.f, 0.f, 0.f};
    float lp[4] = {0.f, 0.f, 0.f, 0.f};

    const int jcol = (jsub << 4) + n16;
    const int j8   = jcol >> 3;
    const int jlo  = jcol & 7;
    const int ksw  = (jq << 2) + quad;

    // K staging (waves 0-3, chunk = w): per-lane global src offset within a
    // K tile = w*512 + n16*32 + quad*8 elems; LDS dest = chunk*1KB + lane*16B.
    const int kst_src = (w << 9) + (n16 << 5) + (quad << 3);
    const int kst_dst = (w << 9) + (lane << 3);
    // K frag ds_read address: buf + jsub*512 + lane*8 elems
    const int krd = (jsub << 9) + (lane << 3);

    // Pre-fragmented V base: cblk = cq*2 (+1 for second frag), jblk = tile*2+jq
    const u16* vfp0 = vb + ((size_t)(cq << 1) << 16) + ((size_t)jq << 9)
                         + ((size_t)((quad << 4) + n16) << 3);
    const u16* vfp1 = vfp0 + 65536;

    bf16x8 kcur, vf0, vf1;

    // ---- prologue: stage K(0)->buf0, K(1)->buf1; prefetch V(0) ----
    if (w < 4) {
        gload_lds16(kb + kst_src,        &Klds[kst_dst]);
        gload_lds16(kb + 2048 + kst_src, &Klds[2048 + kst_dst]);
    }
    vf0 = *(const bf16x8*)(vfp0);
    vf1 = *(const bf16x8*)(vfp1);
    __syncthreads();   // K(0), K(1) in LDS; V(0) in regs

    // ---- phase 0: S(0) into parity 0 ----
    kcur = *(const bf16x8*)&Klds[krd];
    {
        u16* Ps = PsA;
        const f32x4 z = {0.f, 0.f, 0.f, 0.f};
        f32x4 s = __builtin_amdgcn_mfma_f32_16x16x32_bf16(qfrag, kcur, z, 0, 0, 0);
        #pragma unroll
        for (int r = 0; r < 4; ++r) {
            const int qrow = (qsub_s << 4) + (quad << 2) + r;
            float p = exp2f(s[r] - EXP_OFF);
            u32 u = as_u(p) & 0xffff0000u;
            lp[r] += as_f(u);
            Ps[qrow * 64 + ((j8 ^ (qrow & 7)) << 3) + jlo] = (u16)(u >> 16);
        }
    }
    __syncthreads();

    // ---- main loop: ONE barrier per tile ----
    for (int tile = 1; tile < 64; ++tile) {
        const int par  = tile & 1;
        u16* Psc = PsA + (par << 12);
        u16* Psp = PsA + ((par ^ 1) << 12);

        // stage K(tile+1) into buf[(tile+1)&1] (that buf was last read in
        // phase tile-1, separated by the barrier) — full-phase cover
        if (w < 4 && tile < 63) {
            gload_lds16(kb + ((size_t)(tile + 1) << 11) + kst_src,
                        &Klds[(((tile + 1) & 1) << 11) + kst_dst]);
        }
        // K frag for S(tile) from LDS (data staged last phase)
        kcur = *(const bf16x8*)&Klds[((tile & 1) << 11) + krd];

        // PV(tile-1): pa from LDS, vf from prefetched global regs
        bf16x8 pa[4];
        #pragma unroll
        for (int qs = 0; qs < 4; ++qs) {
            const int qrow = (qs << 4) + n16;
            pa[qs] = *(const bf16x8*)&Psp[qrow * 64 + ((ksw ^ (qrow & 7)) << 3)];
        }
        #pragma unroll
        for (int qs = 0; qs < 4; ++qs) {
            acc[qs][0] = __builtin_amdgcn_mfma_f32_16x16x32_bf16(pa[qs], vf0, acc[qs][0], 0, 0, 0);
            acc[qs][1] = __builtin_amdgcn_mfma_f32_16x16x32_bf16(pa[qs], vf1, acc[qs][1], 0, 0, 0);
        }

        // prefetch V-frags for PV(tile) (consumed next phase)
        vf0 = *(const bf16x8*)(vfp0 + ((size_t)tile << 10));
        vf1 = *(const bf16x8*)(vfp1 + ((size_t)tile << 10));

        // S(tile) + softmax + P write
        const f32x4 z = {0.f, 0.f, 0.f, 0.f};
        f32x4 s = __builtin_amdgcn_mfma_f32_16x16x32_bf16(qfrag, kcur, z, 0, 0, 0);
        #pragma unroll
        for (int r = 0; r < 4; ++r) {
            const int qrow = (qsub_s << 4) + (quad << 2) + r;
            float p = exp2f(s[r] - EXP_OFF);
            u32 u = as_u(p) & 0xffff0000u;
            lp[r] += as_f(u);
            Psc[qrow * 64 + ((j8 ^ (qrow & 7)) << 3) + jlo] = (u16)(u >> 16);
        }

        __syncthreads();
    }

    // ---- final PV(63): parity 1, vf holds jblk of tile 63 ----
    {
        u16* Psp = PsA + (1 << 12);
        bf16x8 pa[4];
        #pragma unroll
        for (int qs = 0; qs < 4; ++qs) {
            const int qrow = (qs << 4) + n16;
            pa[qs] = *(const bf16x8*)&Psp[qrow * 64 + ((ksw ^ (qrow & 7)) << 3)];
        }
        #pragma unroll
        for (int qs = 0; qs < 4; ++qs) {
            acc[qs][0] = __builtin_amdgcn_mfma_f32_16x16x32_bf16(pa[qs], vf0, acc[qs][0], 0, 0, 0);
            acc[qs][1] = __builtin_amdgcn_mfma_f32_16x16x32_bf16(pa[qs], vf1, acc[qs][1], 0, 0, 0);
        }
    }

    // ---- l reduction ----
    #pragma unroll
    for (int r = 0; r < 4; ++r) {
        lp[r] += __shfl_xor(lp[r], 1);
        lp[r] += __shfl_xor(lp[r], 2);
        lp[r] += __shfl_xor(lp[r], 4);
        lp[r] += __shfl_xor(lp[r], 8);
    }
    if (n16 == 0) {
        #pragma unroll
        for (int r = 0; r < 4; ++r)
            atomicAdd(&lS[(qsub_s << 4) + (quad << 2) + r], lp[r]);
    }
    __syncthreads();
    if (t < 64) lS[t] = 1.0f / lS[t];
    const bool isf32 = (dtf != 0);

    // ---- epilogue: 4 chunks of 64 c; combine jq-partials in Dbuf, store ----
    for (int chunk = 0; chunk < 4; ++chunk) {
        __syncthreads();   // Dbuf free; rl ready; Ps reads complete (chunk 0)
        if (jq == 1 && (cq >> 1) == chunk) {
            #pragma unroll
            for (int qs = 0; qs < 4; ++qs)
                #pragma unroll
                for (int cs = 0; cs < 2; ++cs)
                    *(f32x4*)&Dbuf[(((cq & 1) << 5) + (cs << 4) + n16) * 68 +
                                   (qs << 4) + (quad << 2)] = acc[qs][cs];
        }
        __syncthreads();
        if (jq == 0 && (cq >> 1) == chunk) {
            #pragma unroll
            for (int qs = 0; qs < 4; ++qs)
                #pragma unroll
                for (int cs = 0; cs < 2; ++cs) {
                    float* p = &Dbuf[(((cq & 1) << 5) + (cs << 4) + n16) * 68 +
                                     (qs << 4) + (quad << 2)];
                    f32x4 d = *(f32x4*)p;
                    d += acc[qs][cs];
                    *(f32x4*)p = d;
                }
        }
        __syncthreads();
        // store: 1024 threads x 4 q
        const int c_l = t >> 4;
        const int qg  = (t & 15) << 2;
        float4 d  = *(float4*)&Dbuf[c_l * 68 + qg];
        float4 rl = *(float4*)&lS[qg];
        const int c_glob = (chunk << 6) + c_l;
        const size_t ob = (((size_t)(n_g * 256 + c_glob)) << 12) + i0 + qg;
        if (isf32) {
            float4 o = make_float4(d.x * rl.x, d.y * rl.y, d.z * rl.z, d.w * rl.w);
            *(float4*)((float*)out + ob) = o;
        } else {
            union { uint2 v; u16 h[4]; } o;
            o.h[0] = f2bf(d.x * rl.x);
            o.h[1] = f2bf(d.y * rl.y);
            o.h[2] = f2bf(d.z * rl.z);
            o.h[3] = f2bf(d.w * rl.w);
            *(uint2*)((u16*)out + ob) = o.v;
        }
    }
}

extern "C" void kernel_launch(void* const* d_in, const int* in_sizes, int n_in,
                              void* d_out, int out_size, void* d_ws, size_t ws_size,
                              hipStream_t stream)
{
    const void* x  = d_in[0];
    const void* Wq = d_in[1];
    const void* bq = d_in[2];
    const void* Wk = d_in[3];
    const void* bk = d_in[4];
    const void* Wv = d_in[5];
    const void* bv = d_in[6];

    const size_t full_need = (size_t)(4u * 4096u) * (32 + 32 + 256) * 2; // 10 MB
    if (ws_size >= full_need) {
        u16* qws = (u16*)d_ws;
        u16* kws = qws + (size_t)4 * 4096 * 32;
        u16* vws = kws + (size_t)4 * 4096 * 32;
        qkv_proj_mfma<<<dim3(1280), dim3(256), 0, stream>>>(
            x, Wq, bq, Wk, bk, Wv, bv, qws, kws, vws, 0, 2);
        flash_mfma11<<<dim3(256), dim3(1024), 0, stream>>>(
            qws, kws, vws, d_out, x, 0, 2);
    } else {
        u16* qws = (u16*)d_ws;
        u16* kws = qws + (size_t)4096 * 32;
        u16* vws = kws + (size_t)4096 * 32;
        for (int n = 0; n < 4; ++n) {
            qkv_proj_mfma<<<dim3(320), dim3(256), 0, stream>>>(
                x, Wq, bq, Wk, bk, Wv, bv, qws, kws, vws, n, 0);
            flash_mfma11<<<dim3(64), dim3(1024), 0, stream>>>(
                qws, kws, vws, d_out, x, n, 0);
        }
    }
}

// Round 10
// 143.672 us; speedup vs baseline: 1.1370x; 1.1370x over previous
//
#include <hip/hip_runtime.h>
#include <hip/hip_bf16.h>
#include <stdint.h>
#include <stddef.h>

typedef unsigned short u16;
typedef unsigned int   u32;
typedef __attribute__((ext_vector_type(8))) short bf16x8;  // 8 bf16 = 4 VGPRs
typedef __attribute__((ext_vector_type(4))) float f32x4;   // MFMA C/D

#define LOG2E   1.44269504f
#define EXP_OFF 23.0831206f   // 16 * log2(e)

static __device__ __forceinline__ float bf2f(u16 v) {
    u32 u = ((u32)v) << 16; float f; __builtin_memcpy(&f, &u, 4); return f;
}
static __device__ __forceinline__ u16 f2bf(float f) {
    u32 u; __builtin_memcpy(&u, &f, 4);
    u32 r = (u + 0x7fffu + ((u >> 16) & 1u)) >> 16; return (u16)r;
}
static __device__ __forceinline__ float as_f(u32 u) { float f; __builtin_memcpy(&f, &u, 4); return f; }
static __device__ __forceinline__ u32   as_u(float f) { u32 u; __builtin_memcpy(&u, &f, 4); return u; }

// fp32-vs-bf16 input detection (wave 0)
static __device__ __forceinline__ int detect_f32_wave0(const void* x, int t) {
    const u32* xw = (const u32*)x;
    int bad = 0;
    #pragma unroll
    for (int k = 0; k < 4; ++k) {
        u32 wv = xw[(t << 2) + k];
        int e = (wv >> 7) & 0xff;
        bad += (e >= 160);
    }
    unsigned long long m = __ballot(bad > 0);
    return (__popcll(m) >= 8) ? 1 : 0;
}

// V workspace layout (pre-fragmented for MFMA B-operand, per batch):
//   elem_addr = cblk*65536 + jblk*512 + (quad4*16 + clo)*8 + jlo
//   where c = cblk*16 + clo, j = jblk*32 + quad4*8 + jlo.
// A wave B-frag load (lane = quad*16+n16 reads 16B) is 1KB fully contiguous.

// ---------------------------------------------------------------------------
// Kernel 1 (MFMA proj, unchanged — verified at R1):
// ---------------------------------------------------------------------------
__global__ __launch_bounds__(256) void qkv_proj_mfma(
    const void* __restrict__ x,
    const void* __restrict__ Wq, const void* __restrict__ bq,
    const void* __restrict__ Wk, const void* __restrict__ bk,
    const void* __restrict__ Wv, const void* __restrict__ bv,
    u16* __restrict__ qws, u16* __restrict__ kws, u16* __restrict__ vws,
    int n_off, int nshiftp)
{
    __shared__ u16 Wl[64 * 256];   // 32 KB, swizzled bf16 W-slice
    __shared__ int dtf;

    const int t    = threadIdx.x;
    const int bid  = blockIdx.x;
    const int n_w  = bid & ((1 << nshiftp) - 1);
    const int rest = bid >> nshiftp;
    const int g    = rest % 5;        // 0 = q+k, 1..4 = v quarters
    const int it   = rest / 5;        // i-tile (64 i)
    const int n_g  = n_off + n_w;
    const int i0   = it << 6;

    if (t < 64) { int f = detect_f32_wave0(x, t); if (t == 0) dtf = f; }
    __syncthreads();
    const bool isf32 = (dtf != 0);

    // ---- stage W slice (64 rows x 256 cols) into LDS, swizzled bf16 ----
    #pragma unroll
    for (int k = 0; k < 16; ++k) {
        int idx  = t + (k << 8);
        int row  = idx >> 6;            // 0..63 (wave-uniform per k)
        int col4 = (idx & 63) << 2;     // 0..252 step 4
        const void* src; int srow;
        if (g == 0) {
            if (row < 32) { src = Wq; srow = row; }
            else          { src = Wk; srow = row - 32; }
        } else { src = Wv; srow = ((g - 1) << 6) + row; }
        ushort4 h;
        if (isf32) {
            float4 wv = *((const float4*)((const float*)src + srow * 256 + col4));
            h.x = f2bf(wv.x); h.y = f2bf(wv.y); h.z = f2bf(wv.z); h.w = f2bf(wv.w);
        } else {
            h = *((const ushort4*)((const u16*)src + srow * 256 + col4));
        }
        *(ushort4*)&Wl[(row << 8) + (col4 ^ ((row & 7) << 3))] = h;
    }
    __syncthreads();

    const int lane = t & 63;
    const int w    = t >> 6;          // wave -> i-frag
    const int n16  = lane & 15;
    const int quad = lane >> 4;
    const int i_b  = i0 + (w << 4);
    const int i    = i_b + n16;
    const int swz  = (n16 & 7) << 3;

    f32x4 acc[4];
    #pragma unroll
    for (int f = 0; f < 4; ++f) acc[f] = (f32x4){0.f, 0.f, 0.f, 0.f};

    // ---- k-loop: 8 chunks of 32 c; A direct-global, B from LDS ----
    if (isf32) {
        const float* xp = (const float*)x
            + (((size_t)(n_g * 256 + (quad << 3))) << 12) + i;
        float af[8];
        #pragma unroll
        for (int e = 0; e < 8; ++e) af[e] = xp[(size_t)e << 12];
        #pragma unroll
        for (int c8 = 0; c8 < 8; ++c8) {
            bf16x8 a;
            #pragma unroll
            for (int e = 0; e < 8; ++e) a[e] = (short)f2bf(af[e]);
            if (c8 < 7) {
                const float* xn = xp + (((size_t)(c8 + 1) << 5) << 12);
                #pragma unroll
                for (int e = 0; e < 8; ++e) af[e] = xn[(size_t)e << 12];
            }
            const int c0 = c8 << 5;
            #pragma unroll
            for (int f = 0; f < 4; ++f) {
                const int brow = (f << 4) + n16;
                bf16x8 b = *(const bf16x8*)
                    &Wl[(brow << 8) + ((c0 + (quad << 3)) ^ swz)];
                acc[f] = __builtin_amdgcn_mfma_f32_16x16x32_bf16(a, b, acc[f], 0, 0, 0);
            }
        }
    } else {
        const u16* xp = (const u16*)x
            + (((size_t)(n_g * 256 + (quad << 3))) << 12) + i;
        u16 af[8];
        #pragma unroll
        for (int e = 0; e < 8; ++e) af[e] = xp[(size_t)e << 12];
        #pragma unroll
        for (int c8 = 0; c8 < 8; ++c8) {
            bf16x8 a;
            #pragma unroll
            for (int e = 0; e < 8; ++e) a[e] = (short)af[e];
            if (c8 < 7) {
                const u16* xn = xp + (((size_t)(c8 + 1) << 5) << 12);
                #pragma unroll
                for (int e = 0; e < 8; ++e) af[e] = xn[(size_t)e << 12];
            }
            const int c0 = c8 << 5;
            #pragma unroll
            for (int f = 0; f < 4; ++f) {
                const int brow = (f << 4) + n16;
                bf16x8 b = *(const bf16x8*)
                    &Wl[(brow << 8) + ((c0 + (quad << 3)) ^ swz)];
                acc[f] = __builtin_amdgcn_mfma_f32_16x16x32_bf16(a, b, acc[f], 0, 0, 0);
            }
        }
    }

    // ---- epilogue: D frag is (col = n16 = och-local, row = quad*4+r = i) ----
    if (g == 0) {
        #pragma unroll
        for (int f = 0; f < 4; ++f) {
            const int ol   = (f << 4) + n16;     // 0..63
            const bool isq = (ol < 32);
            const int och  = isq ? ol : (ol - 32);
            float bias;
            if (isf32) bias = ((const float*)(isq ? bq : bk))[och];
            else       bias = bf2f(((const u16*)(isq ? bq : bk))[och]);
            u16* dst = (isq ? qws : kws) + (((size_t)n_w) << 17) + och;
            const float scale = isq ? LOG2E : 1.0f;
            #pragma unroll
            for (int r = 0; r < 4; ++r) {
                const int ii = i_b + (quad << 2) + r;
                dst[(size_t)ii << 5] = f2bf((acc[f][r] + bias) * scale);
            }
        }
    } else {
        #pragma unroll
        for (int f = 0; f < 4; ++f) {
            const int c = ((g - 1) << 6) + (f << 4) + n16;   // c&15 == n16
            float bias = isf32 ? ((const float*)bv)[c]
                               : bf2f(((const u16*)bv)[c]);
            const int i4 = i_b + (quad << 2);
            ushort4 h;
            h.x = f2bf(acc[f][0] + bias);
            h.y = f2bf(acc[f][1] + bias);
            h.z = f2bf(acc[f][2] + bias);
            h.w = f2bf(acc[f][3] + bias);
            const size_t addr = ((size_t)n_w << 20)
                + ((size_t)(c >> 4) << 16)          // cblk*65536
                + ((size_t)(i4 >> 5) << 9)          // jblk*512
                + (size_t)((((((i4 & 31) >> 3) << 4) + (c & 15)) << 3) + (i4 & 7));
            *(ushort4*)(vws + addr) = h;
        }
    }
}

// ---------------------------------------------------------------------------
// Kernel 2 (v15b): EXACT v12 per-tile schedule (proven 52.3us) + VALU diet:
//   - P-write / pa-read LDS byte offsets hoisted (tile-invariant)
//   - incremental global pointers (kpp += 2048, vp += 1024 elems/tile)
//   - -EXP_OFF folded into S-MFMA C operand (v10/v13-validated)
//   - main loop unrolled in PAIRS with static parity bases (no pointer
//     swap); tile 63 peeled. Barrier count and per-tile ordering identical.
// ---------------------------------------------------------------------------
__global__ __launch_bounds__(1024) void flash_mfma12(
    const u16* __restrict__ qws, const u16* __restrict__ kws,
    const u16* __restrict__ vws, void* __restrict__ out,
    const void* __restrict__ x, int n_off, int nshift)
{
    __shared__ __align__(16) char arena[17920];
    __shared__ __align__(16) float lS[64];
    __shared__ int dtf;
    u16*   PsA  = (u16*)arena;                 // parity 0
    u16*   PsB  = (u16*)arena + 4096;          // parity 1
    float* Dbuf = (float*)arena;               // epilogue alias

    const int t    = threadIdx.x;
    const int lane = t & 63;
    const int w    = t >> 6;          // 0..15
    const int n16  = lane & 15;
    const int quad = lane >> 4;
    const int bid  = blockIdx.x;
    const int n_w  = bid & ((1 << nshift) - 1);
    const int qt   = bid >> nshift;
    const int n_g  = n_off + n_w;
    const int i0   = qt << 6;

    if (t < 64) {
        int f = detect_f32_wave0(x, t);
        if (t == 0) dtf = f;
        lS[t] = 0.f;
    }

    const u16* qb = qws + (((size_t)n_w) << 17);
    const u16* kb = kws + (((size_t)n_w) << 17);
    const u16* vb = vws + (((size_t)n_w) << 20);

    // S decomposition
    const int qsub_s = w & 3;
    const int jsub   = w >> 2;
    // PV decomposition: 32 c x 32 j per wave
    const int cq = w & 7;
    const int jq = w >> 3;

    const bf16x8 qfrag =
        *(const bf16x8*)(qb + ((size_t)(i0 + (qsub_s << 4) + n16) << 5) + (quad << 3));

    f32x4 acc[4][2];
    #pragma unroll
    for (int a = 0; a < 4; ++a)
        #pragma unroll
        for (int b = 0; b < 2; ++b) acc[a][b] = (f32x4){0.f, 0.f, 0.f, 0.f};
    float lp[4] = {0.f, 0.f, 0.f, 0.f};

    const int jcol = (jsub << 4) + n16;
    const int j8   = jcol >> 3;
    const int jlo  = jcol & 7;
    const int ksw  = (jq << 2) + quad;
    const f32x4 zoff = {-EXP_OFF, -EXP_OFF, -EXP_OFF, -EXP_OFF};

    // ---- hoisted LDS byte offsets (tile-invariant) ----
    int pwoff[4];   // P-write: elem (qrow*64 + ((j8^(qrow&7))<<3) + jlo) * 2
    #pragma unroll
    for (int r = 0; r < 4; ++r) {
        const int qrow = (qsub_s << 4) + (quad << 2) + r;
        pwoff[r] = (qrow * 64 + ((j8 ^ (qrow & 7)) << 3) + jlo) << 1;
    }
    int paoff[4];   // pa-read: elem (qrow*64 + ((ksw^(qrow&7))<<3)) * 2
    #pragma unroll
    for (int qs = 0; qs < 4; ++qs) {
        const int qrow = (qs << 4) + n16;
        paoff[qs] = (qrow * 64 + ((ksw ^ (qrow & 7)) << 3)) << 1;
    }

    // K frag pointer: K(T) at kp + T*2048 elems
    const u16* kp = kb + ((size_t)((jsub << 4) + n16) << 5) + (quad << 3);
    // Pre-fragmented V base: cblk = cq*2 (+1 for second frag), jblk = tile*2+jq
    const u16* vfp0 = vb + ((size_t)(cq << 1) << 16) + ((size_t)jq << 9)
                         + ((size_t)((quad << 4) + n16) << 3);
    const u16* vfp1 = vfp0 + 65536;

    bf16x8 kcur, knext, vf0, vf1;

    // ---- prologue: S(0) into parity 0; prefetch K(1), V-frags for PV(0) ----
    kcur = *(const bf16x8*)(kp);
    {
        f32x4 s = __builtin_amdgcn_mfma_f32_16x16x32_bf16(qfrag, kcur, zoff, 0, 0, 0);
        #pragma unroll
        for (int r = 0; r < 4; ++r) {
            float p = exp2f(s[r]);
            u32 u = as_u(p) & 0xffff0000u;
            lp[r] += as_f(u);
            *(u16*)((char*)PsA + pwoff[r]) = (u16)(u >> 16);
        }
        knext = *(const bf16x8*)(kp + 2048);
        vf0 = *(const bf16x8*)(vfp0);
        vf1 = *(const bf16x8*)(vfp1);
    }
    __syncthreads();

    // ---- main loop: tiles 1..62 in pairs (static parity bases), 63 peeled.
    //      Per-tile ordering identical to v12: K(t+1) issue first, PV(t-1),
    //      V(t) prefetch, S(t), barrier. ----
    const u16* kpp = kp + 2 * 2048;  // K(2)
    const u16* vp0 = vfp0 + 1024;    // V(1)
    const u16* vp1 = vfp1 + 1024;

    for (int tile = 1; tile < 63; tile += 2) {
        // ===== odd tile: read PsA (parity 0), write PsB (parity 1) =====
        kcur = knext;
        knext = *(const bf16x8*)(kpp);   // K(tile+1), tile+1 <= 62
        kpp += 2048;
        {
            bf16x8 pa[4];
            #pragma unroll
            for (int qs = 0; qs < 4; ++qs)
                pa[qs] = *(const bf16x8*)((const char*)PsA + paoff[qs]);
            #pragma unroll
            for (int qs = 0; qs < 4; ++qs) {
                acc[qs][0] = __builtin_amdgcn_mfma_f32_16x16x32_bf16(pa[qs], vf0, acc[qs][0], 0, 0, 0);
                acc[qs][1] = __builtin_amdgcn_mfma_f32_16x16x32_bf16(pa[qs], vf1, acc[qs][1], 0, 0, 0);
            }
            vf0 = *(const bf16x8*)(vp0);
            vf1 = *(const bf16x8*)(vp1);
            vp0 += 1024; vp1 += 1024;
            f32x4 s = __builtin_amdgcn_mfma_f32_16x16x32_bf16(qfrag, kcur, zoff, 0, 0, 0);
            #pragma unroll
            for (int r = 0; r < 4; ++r) {
                float p = exp2f(s[r]);
                u32 u = as_u(p) & 0xffff0000u;
                lp[r] += as_f(u);
                *(u16*)((char*)PsB + pwoff[r]) = (u16)(u >> 16);
            }
        }
        __syncthreads();

        // ===== even tile (tile+1): read PsB, write PsA =====
        kcur = knext;
        knext = *(const bf16x8*)(kpp);   // K(tile+2), tile+2 <= 63
        kpp += 2048;
        {
            bf16x8 pa[4];
            #pragma unroll
            for (int qs = 0; qs < 4; ++qs)
                pa[qs] = *(const bf16x8*)((const char*)PsB + paoff[qs]);
            #pragma unroll
            for (int qs = 0; qs < 4; ++qs) {
                acc[qs][0] = __builtin_amdgcn_mfma_f32_16x16x32_bf16(pa[qs], vf0, acc[qs][0], 0, 0, 0);
                acc[qs][1] = __builtin_amdgcn_mfma_f32_16x16x32_bf16(pa[qs], vf1, acc[qs][1], 0, 0, 0);
            }
            vf0 = *(const bf16x8*)(vp0);
            vf1 = *(const bf16x8*)(vp1);
            vp0 += 1024; vp1 += 1024;
            f32x4 s = __builtin_amdgcn_mfma_f32_16x16x32_bf16(qfrag, kcur, zoff, 0, 0, 0);
            #pragma unroll
            for (int r = 0; r < 4; ++r) {
                float p = exp2f(s[r]);
                u32 u = as_u(p) & 0xffff0000u;
                lp[r] += as_f(u);
                *(u16*)((char*)PsA + pwoff[r]) = (u16)(u >> 16);
            }
        }
        __syncthreads();
    }

    // ===== tile 63 (odd): read PsA, write PsB; kcur = K(63) from knext =====
    {
        kcur = knext;
        bf16x8 pa[4];
        #pragma unroll
        for (int qs = 0; qs < 4; ++qs)
            pa[qs] = *(const bf16x8*)((const char*)PsA + paoff[qs]);
        #pragma unroll
        for (int qs = 0; qs < 4; ++qs) {
            acc[qs][0] = __builtin_amdgcn_mfma_f32_16x16x32_bf16(pa[qs], vf0, acc[qs][0], 0, 0, 0);
            acc[qs][1] = __builtin_amdgcn_mfma_f32_16x16x32_bf16(pa[qs], vf1, acc[qs][1], 0, 0, 0);
        }
        vf0 = *(const bf16x8*)(vp0);   // V(63)
        vf1 = *(const bf16x8*)(vp1);
        f32x4 s = __builtin_amdgcn_mfma_f32_16x16x32_bf16(qfrag, kcur, zoff, 0, 0, 0);
        #pragma unroll
        for (int r = 0; r < 4; ++r) {
            float p = exp2f(s[r]);
            u32 u = as_u(p) & 0xffff0000u;
            lp[r] += as_f(u);
            *(u16*)((char*)PsB + pwoff[r]) = (u16)(u >> 16);
        }
    }
    __syncthreads();

    // ---- final PV(63): reads PsB (parity 1) ----
    {
        bf16x8 pa[4];
        #pragma unroll
        for (int qs = 0; qs < 4; ++qs)
            pa[qs] = *(const bf16x8*)((const char*)PsB + paoff[qs]);
        #pragma unroll
        for (int qs = 0; qs < 4; ++qs) {
            acc[qs][0] = __builtin_amdgcn_mfma_f32_16x16x32_bf16(pa[qs], vf0, acc[qs][0], 0, 0, 0);
            acc[qs][1] = __builtin_amdgcn_mfma_f32_16x16x32_bf16(pa[qs], vf1, acc[qs][1], 0, 0, 0);
        }
    }

    // ---- l reduction ----
    #pragma unroll
    for (int r = 0; r < 4; ++r) {
        lp[r] += __shfl_xor(lp[r], 1);
        lp[r] += __shfl_xor(lp[r], 2);
        lp[r] += __shfl_xor(lp[r], 4);
        lp[r] += __shfl_xor(lp[r], 8);
    }
    if (n16 == 0) {
        #pragma unroll
        for (int r = 0; r < 4; ++r)
            atomicAdd(&lS[(qsub_s << 4) + (quad << 2) + r], lp[r]);
    }
    __syncthreads();
    if (t < 64) lS[t] = 1.0f / lS[t];
    const bool isf32 = (dtf != 0);

    // ---- epilogue: 4 chunks of 64 c; combine jq-partials in Dbuf, store ----
    for (int chunk = 0; chunk < 4; ++chunk) {
        __syncthreads();   // Dbuf free; rl ready; Ps reads complete (chunk 0)
        if (jq == 1 && (cq >> 1) == chunk) {
            #pragma unroll
            for (int qs = 0; qs < 4; ++qs)
                #pragma unroll
                for (int cs = 0; cs < 2; ++cs)
                    *(f32x4*)&Dbuf[(((cq & 1) << 5) + (cs << 4) + n16) * 68 +
                                   (qs << 4) + (quad << 2)] = acc[qs][cs];
        }
        __syncthreads();
        if (jq == 0 && (cq >> 1) == chunk) {
            #pragma unroll
            for (int qs = 0; qs < 4; ++qs)
                #pragma unroll
                for (int cs = 0; cs < 2; ++cs) {
                    float* p = &Dbuf[(((cq & 1) << 5) + (cs << 4) + n16) * 68 +
                                     (qs << 4) + (quad << 2)];
                    f32x4 d = *(f32x4*)p;
                    d += acc[qs][cs];
                    *(f32x4*)p = d;
                }
        }
        __syncthreads();
        // store: 1024 threads x 4 q
        const int c_l = t >> 4;
        const int qg  = (t & 15) << 2;
        float4 d  = *(float4*)&Dbuf[c_l * 68 + qg];
        float4 rl = *(float4*)&lS[qg];
        const int c_glob = (chunk << 6) + c_l;
        const size_t ob = (((size_t)(n_g * 256 + c_glob)) << 12) + i0 + qg;
        if (isf32) {
            float4 o = make_float4(d.x * rl.x, d.y * rl.y, d.z * rl.z, d.w * rl.w);
            *(float4*)((float*)out + ob) = o;
        } else {
            union { uint2 v; u16 h[4]; } o;
            o.h[0] = f2bf(d.x * rl.x);
            o.h[1] = f2bf(d.y * rl.y);
            o.h[2] = f2bf(d.z * rl.z);
            o.h[3] = f2bf(d.w * rl.w);
            *(uint2*)((u16*)out + ob) = o.v;
        }
    }
}

extern "C" void kernel_launch(void* const* d_in, const int* in_sizes, int n_in,
                              void* d_out, int out_size, void* d_ws, size_t ws_size,
                              hipStream_t stream)
{
    const void* x  = d_in[0];
    const void* Wq = d_in[1];
    const void* bq = d_in[2];
    const void* Wk = d_in[3];
    const void* bk = d_in[4];
    const void* Wv = d_in[5];
    const void* bv = d_in[6];

    const size_t full_need = (size_t)(4u * 4096u) * (32 + 32 + 256) * 2; // 10 MB
    if (ws_size >= full_need) {
        u16* qws = (u16*)d_ws;
        u16* kws = qws + (size_t)4 * 4096 * 32;
        u16* vws = kws + (size_t)4 * 4096 * 32;
        qkv_proj_mfma<<<dim3(1280), dim3(256), 0, stream>>>(
            x, Wq, bq, Wk, bk, Wv, bv, qws, kws, vws, 0, 2);
        flash_mfma12<<<dim3(256), dim3(1024), 0, stream>>>(
            qws, kws, vws, d_out, x, 0, 2);
    } else {
        u16* qws = (u16*)d_ws;
        u16* kws = qws + (size_t)4096 * 32;
        u16* vws = kws + (size_t)4096 * 32;
        for (int n = 0; n < 4; ++n) {
            qkv_proj_mfma<<<dim3(320), dim3(256), 0, stream>>>(
                x, Wq, bq, Wk, bk, Wv, bv, qws, kws, vws, n, 0);
            flash_mfma12<<<dim3(64), dim3(1024), 0, stream>>>(
                qws, kws, vws, d_out, x, n, 0);
        }
    }
}